// Round 1
// baseline (946.472 us; speedup 1.0000x reference)
//
#include <hip/hip_runtime.h>

// Problem constants
#define H   512
#define W   512
#define C   256
#define KH  11
#define KW  11
#define OH  502
#define OW  502
#define OUT_MAP (OH * OW)   // 252004

// Tiling
#define TX 4                 // output px per thread, x
#define TY 4                 // output px per thread, y
#define TILE_X 64            // 16 threads * TX
#define TILE_Y 64            // 16 threads * TY
#define IN_X  (TILE_X + KW - 1)   // 74
#define IN_Y  (TILE_Y + KH - 1)   // 74
#define IN_XP 76                  // padded LDS row stride (floats)
#define CPB   32                  // channels per block (z-split 8)
#define VEC_PER_ROW 19            // 19 float4 = 76 floats staged per row

__global__ __launch_bounds__(256, 2)
void conv_kernel(const float* __restrict__ x, const float* __restrict__ w,
                 float* __restrict__ out)
{
    __shared__ float s_in[IN_Y * IN_XP];   // 74*76*4 = 22496 B

    const int tid = threadIdx.x;
    const int tx  = tid & 15;
    const int ty  = tid >> 4;
    const int x0  = blockIdx.x * TILE_X;
    const int y0  = blockIdx.y * TILE_Y;
    const int c0  = blockIdx.z * CPB;

    float acc[TY][TX];
#pragma unroll
    for (int dy = 0; dy < TY; ++dy)
#pragma unroll
        for (int i = 0; i < TX; ++i) acc[dy][i] = 0.f;

    const int ry0 = ty * TY;
    const int cx0 = tx * TX;

    for (int cc = 0; cc < CPB; ++cc) {
        const int c = c0 + cc;
        const float* __restrict__ xb0 = x + (size_t)c * (H * W);
        const float* __restrict__ xb1 = xb0 + (size_t)C * H * W;

        // ---- stage batch-summed input tile into LDS ----
        for (int i = tid; i < IN_Y * VEC_PER_ROW; i += 256) {
            const int row = i / VEC_PER_ROW;
            const int vec = i - row * VEC_PER_ROW;
            const int gy  = y0 + row;
            const int gx  = x0 + vec * 4;
            float4 v = make_float4(0.f, 0.f, 0.f, 0.f);
            if (gy < H) {
                if (gx + 3 < W) {
                    const float4 a = *(const float4*)(xb0 + (size_t)gy * W + gx);
                    const float4 b = *(const float4*)(xb1 + (size_t)gy * W + gx);
                    v = make_float4(a.x + b.x, a.y + b.y, a.z + b.z, a.w + b.w);
                } else {
                    float t[4] = {0.f, 0.f, 0.f, 0.f};
#pragma unroll
                    for (int j = 0; j < 4; ++j)
                        if (gx + j < W)
                            t[j] = xb0[(size_t)gy * W + gx + j] + xb1[(size_t)gy * W + gx + j];
                    v = make_float4(t[0], t[1], t[2], t[3]);
                }
            }
            *(float4*)&s_in[row * IN_XP + vec * 4] = v;
        }
        __syncthreads();

        // ---- compute: sliding-row window, weights via uniform scalar loads ----
        const float* __restrict__ wc = w + (size_t)c * (KH * KW);
#pragma unroll
        for (int r = 0; r < TY + KH - 1; ++r) {      // 14 rows
            const float* rp = &s_in[(ry0 + r) * IN_XP + cx0];
            const float4 a0 = *(const float4*)(rp + 0);
            const float4 a1 = *(const float4*)(rp + 4);
            const float4 a2 = *(const float4*)(rp + 8);
            const float4 a3 = *(const float4*)(rp + 12);
            const float win[16] = {a0.x, a0.y, a0.z, a0.w,
                                   a1.x, a1.y, a1.z, a1.w,
                                   a2.x, a2.y, a2.z, a2.w,
                                   a3.x, a3.y, a3.z, a3.w};
#pragma unroll
            for (int dy = 0; dy < TY; ++dy) {
                const int kh = r - dy;
                if (kh >= 0 && kh < KH) {
#pragma unroll
                    for (int kw = 0; kw < KW; ++kw) {
                        const float wv = wc[kh * KW + kw];   // uniform -> s_load
#pragma unroll
                        for (int i = 0; i < TX; ++i)
                            acc[dy][i] += win[kw + i] * wv;
                    }
                }
            }
        }
        __syncthreads();
    }

    // ---- accumulate partials into bias-initialized output (batch 0 map) ----
#pragma unroll
    for (int dy = 0; dy < TY; ++dy) {
        const int oy = y0 + ry0 + dy;
        if (oy < OH) {
#pragma unroll
            for (int i = 0; i < TX; ++i) {
                const int ox = x0 + cx0 + i;
                if (ox < OW)
                    atomicAdd(&out[(size_t)oy * OW + ox], acc[dy][i]);
            }
        }
    }
}

__global__ void init_kernel(float* __restrict__ out, const float* __restrict__ bias)
{
    const int i = blockIdx.x * 256 + threadIdx.x;
    if (i < OUT_MAP) out[i] = bias[0];
}

__global__ void bcast_kernel(float* __restrict__ out)
{
    const int i = blockIdx.x * 256 + threadIdx.x;
    if (i < OUT_MAP) out[OUT_MAP + i] = out[i];
}

extern "C" void kernel_launch(void* const* d_in, const int* in_sizes, int n_in,
                              void* d_out, int out_size, void* d_ws, size_t ws_size,
                              hipStream_t stream)
{
    const float* x    = (const float*)d_in[0];   // (2,256,512,512) fp32
    const float* w    = (const float*)d_in[1];   // (1,256,11,11)  fp32
    const float* bias = (const float*)d_in[2];   // (1,)           fp32
    float* out = (float*)d_out;                  // (2,1,502,502)  fp32

    const int nb = (OUT_MAP + 255) / 256;
    init_kernel<<<nb, 256, 0, stream>>>(out, bias);
    conv_kernel<<<dim3(8, 8, 8), 256, 0, stream>>>(x, w, out);
    bcast_kernel<<<nb, 256, 0, stream>>>(out);
}

// Round 2
// 829.116 us; speedup vs baseline: 1.1415x; 1.1415x over previous
//
#include <hip/hip_runtime.h>

// Problem constants
#define H   512
#define W   512
#define C   256
#define KH  11
#define KW  11
#define OH  502
#define OW  502
#define OUT_MAP (OH * OW)   // 252004
#define HWSZ (H * W)

// Tiling
#define TX 4                 // output px per thread, x
#define TY 4                 // output px per thread, y
#define TILE_X 64            // 16 threads * TX
#define TILE_Y 64            // 16 threads * TY
#define IN_X  (TILE_X + KW - 1)   // 74
#define IN_Y  (TILE_Y + KH - 1)   // 74
#define IN_XP 76                  // padded LDS row stride (floats)
#define CPB   8                   // channels per block (z-split 32)
#define VEC_PER_ROW 19            // 19 float4 = 76 floats staged per row
#define NSTAGE_TOT (IN_Y * VEC_PER_ROW)   // 1406 float4 slots
#define NSTAGE_IT  6                      // ceil(1406/256)

__global__ __launch_bounds__(256, 7)
void conv_kernel(const float* __restrict__ x, const float* __restrict__ w,
                 float* __restrict__ out)
{
    __shared__ float s_in[IN_Y * IN_XP];   // 74*76*4 = 22496 B -> 7 blocks/CU

    const int tid = threadIdx.x;
    const int tx  = tid & 15;
    const int ty  = tid >> 4;
    const int x0  = blockIdx.x * TILE_X;
    const int y0  = blockIdx.y * TILE_Y;
    const int c0  = blockIdx.z * CPB;

    // ---- precompute channel-invariant staging descriptors ----
    // Out-of-range addresses are CLAMPED, not zeroed: garbage cells are only
    // ever read by out-of-range outputs, which are discarded at the epilogue.
    int s_goff[NSTAGE_IT];   // element offset within one channel slab
    int s_loff[NSTAGE_IT];   // LDS float offset
    bool s_act[NSTAGE_IT];
#pragma unroll
    for (int j = 0; j < NSTAGE_IT; ++j) {
        int i = tid + j * 256;
        const bool act = (i < NSTAGE_TOT);
        if (!act) i = 0;
        const int row = i / VEC_PER_ROW;
        const int vec = i - row * VEC_PER_ROW;
        const int gy  = min(y0 + row, H - 1);
        const int gx  = min(x0 + vec * 4, W - 4);
        s_goff[j] = gy * W + gx;
        s_loff[j] = row * IN_XP + vec * 4;
        s_act[j]  = act;
    }

    float acc[TY][TX];
#pragma unroll
    for (int dy = 0; dy < TY; ++dy)
#pragma unroll
        for (int i = 0; i < TX; ++i) acc[dy][i] = 0.f;

    const int ry0 = ty * TY;
    const int cx0 = tx * TX;

    for (int cc = 0; cc < CPB; ++cc) {
        const int c = c0 + cc;
        const float* __restrict__ p0 = x + (size_t)c * HWSZ;           // batch 0
        const float* __restrict__ p1 = p0 + (size_t)C * HWSZ;          // batch 1

        // ---- stage batch-summed input tile into LDS ----
#pragma unroll
        for (int j = 0; j < NSTAGE_IT; ++j) {
            if (s_act[j]) {
                const float4 a = *(const float4*)(p0 + s_goff[j]);
                const float4 b = *(const float4*)(p1 + s_goff[j]);
                *(float4*)&s_in[s_loff[j]] =
                    make_float4(a.x + b.x, a.y + b.y, a.z + b.z, a.w + b.w);
            }
        }
        __syncthreads();

        // ---- compute: sliding-row window, weights via uniform scalar loads ----
        const float* __restrict__ wc = w + (size_t)c * (KH * KW);
#pragma unroll
        for (int r = 0; r < TY + KH - 1; ++r) {      // 14 rows
            const float* rp = &s_in[(ry0 + r) * IN_XP + cx0];
            const float4 a0 = *(const float4*)(rp + 0);
            const float4 a1 = *(const float4*)(rp + 4);
            const float4 a2 = *(const float4*)(rp + 8);
            const float4 a3 = *(const float4*)(rp + 12);
            const float win[16] = {a0.x, a0.y, a0.z, a0.w,
                                   a1.x, a1.y, a1.z, a1.w,
                                   a2.x, a2.y, a2.z, a2.w,
                                   a3.x, a3.y, a3.z, a3.w};
#pragma unroll
            for (int dy = 0; dy < TY; ++dy) {
                const int kh = r - dy;
                if (kh >= 0 && kh < KH) {
#pragma unroll
                    for (int kw = 0; kw < KW; ++kw) {
                        const float wv = wc[kh * KW + kw];   // uniform -> s_load
#pragma unroll
                        for (int i = 0; i < TX; ++i)
                            acc[dy][i] += win[kw + i] * wv;
                    }
                }
            }
        }
        __syncthreads();
    }

    // ---- accumulate partials into bias-initialized output (batch 0 map) ----
#pragma unroll
    for (int dy = 0; dy < TY; ++dy) {
        const int oy = y0 + ry0 + dy;
        if (oy < OH) {
#pragma unroll
            for (int i = 0; i < TX; ++i) {
                const int ox = x0 + cx0 + i;
                if (ox < OW)
                    atomicAdd(&out[(size_t)oy * OW + ox], acc[dy][i]);
            }
        }
    }
}

__global__ void init_kernel(float* __restrict__ out, const float* __restrict__ bias)
{
    const int i = blockIdx.x * 256 + threadIdx.x;
    if (i < OUT_MAP) out[i] = bias[0];
}

__global__ void bcast_kernel(float* __restrict__ out)
{
    const int i = blockIdx.x * 256 + threadIdx.x;
    if (i < OUT_MAP) out[OUT_MAP + i] = out[i];
}

extern "C" void kernel_launch(void* const* d_in, const int* in_sizes, int n_in,
                              void* d_out, int out_size, void* d_ws, size_t ws_size,
                              hipStream_t stream)
{
    const float* x    = (const float*)d_in[0];   // (2,256,512,512) fp32
    const float* w    = (const float*)d_in[1];   // (1,256,11,11)  fp32
    const float* bias = (const float*)d_in[2];   // (1,)           fp32
    float* out = (float*)d_out;                  // (2,1,502,502)  fp32

    const int nb = (OUT_MAP + 255) / 256;
    init_kernel<<<nb, 256, 0, stream>>>(out, bias);
    conv_kernel<<<dim3(8, 8, 32), 256, 0, stream>>>(x, w, out);
    bcast_kernel<<<nb, 256, 0, stream>>>(out);
}